// Round 10
// baseline (432.958 us; speedup 1.0000x reference)
//
#include <hip/hip_runtime.h>

#define B_ 16
#define T_ 128
#define OBS_ 64
#define SLOTS_ 67
#define E_ 32
#define H_ 4
#define HD_ 8
#define FFN_ 64

typedef _Float16 h2 __attribute__((ext_vector_type(2)));
typedef _Float16 h8 __attribute__((ext_vector_type(8)));
typedef __fp16 mh8 __attribute__((ext_vector_type(8)));
typedef float fx4 __attribute__((ext_vector_type(4)));
union H8 { h8 v; h2 h[4]; };

// fp16 weight block layout (halves): Wq 0 | Wk 1024 | Wv 2048 | Wo 3072 |
// Wg 4096 | Wvl 6144 | Wout 8192  (10240 halves per transformer block)
#define WBLK 10240
#define X16_BYTES (B_ * T_ * SLOTS_ * E_ * 2)  // 8,781,824 (X stored fp16)

__device__ __forceinline__ float red32(float v) {
  v += __shfl_xor(v, 16); v += __shfl_xor(v, 8); v += __shfl_xor(v, 4);
  v += __shfl_xor(v, 2);  v += __shfl_xor(v, 1);
  return v;
}
__device__ __forceinline__ float red8(float v) {
  v += __shfl_xor(v, 4); v += __shfl_xor(v, 2); v += __shfl_xor(v, 1);
  return v;
}
__device__ __forceinline__ float fdot2(h2 a, h2 b, float c) {
  return __builtin_amdgcn_fdot2(a, b, c, false);
}
__device__ __forceinline__ h2 pkrtz(float x, float y) {
  return __builtin_bit_cast(h2, __builtin_amdgcn_cvt_pkrtz(x, y));
}
__device__ __forceinline__ fx4 mfma16(h8 a, h8 b, fx4 c) {
  return __builtin_amdgcn_mfma_f32_16x16x32_f16(
      __builtin_bit_cast(mh8, a), __builtin_bit_cast(mh8, b), c, 0, 0, 0);
}

// ---------------- weight pre-conversion to fp16 ----------------
struct WPtrs {
  const float *sWq, *sWk, *sWv, *sWo, *sWg, *sWvl, *sWout;
  const float *tWq, *tWk, *tWv, *tWo, *tWg, *tWvl, *tWout;
};

__global__ __launch_bounds__(256) void cvt_weights_kernel(WPtrs p, _Float16* dst) {
  int i = blockIdx.x * 256 + threadIdx.x;  // pair index
  const int total_pairs = 5 * WBLK / 2;    // 25600
  if (i >= total_pairs) return;
  int blk = i / (WBLK / 2);
  int f = (i % (WBLK / 2)) * 2;
  bool sp = blk < 3;
  int bi = sp ? blk : blk - 3;
  const float* src;
  int o;
  if (f < 1024)      { src = (sp ? p.sWq : p.tWq) + bi * 1024;  o = f; }
  else if (f < 2048) { src = (sp ? p.sWk : p.tWk) + bi * 1024;  o = f - 1024; }
  else if (f < 3072) { src = (sp ? p.sWv : p.tWv) + bi * 1024;  o = f - 2048; }
  else if (f < 4096) { src = (sp ? p.sWo : p.tWo) + bi * 1024;  o = f - 3072; }
  else if (f < 6144) { src = (sp ? p.sWg : p.tWg) + bi * 2048;  o = f - 4096; }
  else if (f < 8192) { src = (sp ? p.sWvl : p.tWvl) + bi * 2048; o = f - 6144; }
  else               { src = (sp ? p.sWout : p.tWout) + bi * 2048; o = f - 8192; }
  ((h2*)dst)[i] = pkrtz(src[o], src[o + 1]);
}

// ---------------- embed + input rmsnorm (writes fp16 X) ----------------
__global__ __launch_bounds__(256) void embed_kernel(
    const float* __restrict__ obs, const float* __restrict__ Wval,
    const float* __restrict__ bval, const float* __restrict__ innw,
    const float* __restrict__ dimemb, const float* __restrict__ cls,
    _Float16* __restrict__ X) {
  int tok = blockIdx.x * 8 + (threadIdx.x >> 5);
  int e = threadIdx.x & 31;
  const int total = B_ * T_ * SLOTS_;
  if (tok >= total) return;
  int slot = tok % SLOTS_;
  int bt = tok / SLOTS_;
  float v;
  if (slot < OBS_) {
    float o = obs[bt * OBS_ + slot];
    v = o * Wval[e] + bval[e] + dimemb[slot * E_ + e];
  } else {
    v = cls[(slot - OBS_) * E_ + e];
  }
  float ss = red32(v * v);
  X[tok * E_ + e] = (_Float16)(v * rsqrtf(ss * (1.0f / E_) + 1e-6f) * innw[e]);
}

// ================= full attention block, MFMA GEMM phases =================
// SV = valid rows, SP = padded rows (multiple of 16).
// LDS (halves): [hb SP*32 | qb SP*32 | kb SP*32 | vb SP*32].
//   hb: h -> o -> h2 ; ffnb (SV*64) overlays qb+kb ; ao scratch = qb ;
//   out scratch = vb.
// Spatial handles 2 sequences as one contiguous 134-row slab.
template <int SV, int SP, bool TEMPORAL>
__device__ __forceinline__ void block_body(
    _Float16* __restrict__ X, const _Float16* __restrict__ W16,
    const float* __restrict__ norm4, const float* __restrict__ qkn, int bid) {
  constexpr int SREG = (SV + 7) / 8;
  constexpr int MT = SP / 16;
  __shared__ __align__(16) _Float16 smem[SP * 128];
  _Float16* hb = smem;
  _Float16* qb = smem + SP * 32;
  _Float16* kb = smem + SP * 64;
  _Float16* vb = smem + SP * 96;
  _Float16* ffnb = qb;  // SV*64 <= SP*64 halves over qb+kb
  _Float16* aob = qb;   // ao scratch (q dead after attention)
  _Float16* outb = vb;  // out scratch (v dead after attention)

  const int tid = threadIdx.x;
  const int e = tid & 31, srow = tid >> 5;
  const int l = tid & 63, wv = tid >> 6;
  const int lm = l & 15, lq = l >> 4, hd = l & 7;

  int base, stride;
  if (TEMPORAL) {
    int b = bid / SLOTS_;
    int slot = bid % SLOTS_;
    base = (b * T_ * SLOTS_ + slot) * E_;
    stride = SLOTS_ * E_;
  } else {
    base = bid * 2 * SLOTS_ * E_;  // contiguous 134-row slab
    stride = E_;
  }

  const float nw0 = norm4[e], nw1 = norm4[E_ + e], nw2 = norm4[2 * E_ + e],
              nw3 = norm4[3 * E_ + e];
  const fx4 fz = {0.f, 0.f, 0.f, 0.f};
  const float qw = qkn[hd], kw = qkn[8 + hd];
  const float qscale = 0.35355339059327373f * 1.4426950408889634f;  // 1/sqrt(8)*log2e
  float theta = 0.f;
  if (TEMPORAL) theta = exp2f(-(float)(hd & 3) * 3.3219280948873623f);

  // ---- phase 1: x -> regs (all loads first, then process) ----
  float xr[SREG];
#pragma unroll
  for (int k = 0; k < SREG; k++) {
    int r = srow + 8 * k;
    if (SV % 8 == 0 || r < SV) xr[k] = (float)X[base + r * stride + e];
  }
#pragma unroll
  for (int k = 0; k < SREG; k++) {
    int r = srow + 8 * k;
    if (SV % 8 == 0 || r < SV) {
      float ss = red32(xr[k] * xr[k]);
      hb[r * 32 + e] = (_Float16)(xr[k] * rsqrtf(ss * (1.0f / E_) + 1e-6f) * nw0);
    }
  }
  __syncthreads();

  // ---- phase 2: q/k/v = MFMA(h, W) + head rmsnorm + RoPE ----
  for (int u = wv; u < MT * 2; u += 4) {
    const int mt = u >> 1, nt = u & 1;
    h8 aH = *(const h8*)(hb + (mt * 16 + lm) * 32 + lq * 8);
    float rc[4], rs[4];
    if (TEMPORAL) {
#pragma unroll
      for (int r = 0; r < 4; r++) {
        float ang = (float)(mt * 16 + lq * 4 + r) * theta;
        __sincosf(ang, &rs[r], &rc[r]);
      }
    }
    const int d = nt * 16 + lm;
    h8 bq = *(const h8*)(W16 + (nt * 16 + lm) * 32 + lq * 8);
    h8 bk = *(const h8*)(W16 + 1024 + (nt * 16 + lm) * 32 + lq * 8);
    h8 bv = *(const h8*)(W16 + 2048 + (nt * 16 + lm) * 32 + lq * 8);
    fx4 aq = mfma16(aH, bq, fz);
    fx4 ak = mfma16(aH, bk, fz);
    fx4 av = mfma16(aH, bv, fz);
#pragma unroll
    for (int r = 0; r < 4; r++) {
      int s = mt * 16 + lq * 4 + r;
      float q1 = aq[r], k1 = ak[r];
      float qv = q1 * rsqrtf(red8(q1 * q1) * 0.125f + 1e-6f) * qw;
      float kv = k1 * rsqrtf(red8(k1 * k1) * 0.125f + 1e-6f) * kw;
      if (TEMPORAL) {
        float qp = __shfl_xor(qv, 4);
        float kp = __shfl_xor(kv, 4);
        qv = (hd < 4) ? (qv * rc[r] - qp * rs[r]) : (qv * rc[r] + qp * rs[r]);
        kv = (hd < 4) ? (kv * rc[r] - kp * rs[r]) : (kv * rc[r] + kp * rs[r]);
      }
      if (SV == SP || s < SV) {
        qb[s * 32 + d] = (_Float16)(qv * qscale);  // exp2-ready
        kb[s * 32 + d] = (_Float16)kv;
        vb[s * 32 + d] = (_Float16)av[r];
      }
    }
  }
  __syncthreads();

  // ---- phase 3: attention (scalar, single-pass softmax; scores bounded) ----
  {
    constexpr int NITEM = 2 * SV;
    constexpr int NPASS = (NITEM + 255) / 256;
    constexpr int KLEN = TEMPORAL ? SV : SLOTS_;
#pragma unroll
    for (int pass = 0; pass < NPASS; pass++) {
      int I = tid + pass * 256;
      if (I < NITEM) {
        int r = I >> 1, hp = I & 1;
        int kb0 = TEMPORAL ? 0 : (r >= SLOTS_ ? SLOTS_ : 0);
        const _Float16* qp_ = qb + r * 32 + hp * 16;
        H8 qfa, qfb;
        qfa.v = *(const h8*)qp_;
        qfb.v = *(const h8*)(qp_ + 8);
        float l0 = 0.f, l1 = 0.f;
        h2 acc[8] = {};
        const _Float16* kp_ = kb + kb0 * 32 + hp * 16;
        const _Float16* vp_ = vb + kb0 * 32 + hp * 16;
#pragma unroll 4
        for (int k = 0; k < KLEN; k++) {
          H8 kfa, kfb, vfa, vfb;
          kfa.v = *(const h8*)kp_;
          kfb.v = *(const h8*)(kp_ + 8);
          vfa.v = *(const h8*)vp_;
          vfb.v = *(const h8*)(vp_ + 8);
          kp_ += 32; vp_ += 32;
          float s0 = fdot2(qfa.h[0], kfa.h[0], fdot2(qfa.h[1], kfa.h[1],
                     fdot2(qfa.h[2], kfa.h[2], fdot2(qfa.h[3], kfa.h[3], 0.f))));
          float s1 = fdot2(qfb.h[0], kfb.h[0], fdot2(qfb.h[1], kfb.h[1],
                     fdot2(qfb.h[2], kfb.h[2], fdot2(qfb.h[3], kfb.h[3], 0.f))));
          float e0 = __builtin_amdgcn_exp2f(s0);
          float e1 = __builtin_amdgcn_exp2f(s1);
          l0 += e0; l1 += e1;
          h2 p0 = pkrtz(e0, e0);
          h2 p1 = pkrtz(e1, e1);
          acc[0] += p0 * vfa.h[0]; acc[1] += p0 * vfa.h[1];
          acc[2] += p0 * vfa.h[2]; acc[3] += p0 * vfa.h[3];
          acc[4] += p1 * vfb.h[0]; acc[5] += p1 * vfb.h[1];
          acc[6] += p1 * vfb.h[2]; acc[7] += p1 * vfb.h[3];
        }
        float iv0 = 1.0f / l0, iv1 = 1.0f / l1;
        h2 il0 = pkrtz(iv0, iv0), il1 = pkrtz(iv1, iv1);
        H8 o0, o1;
#pragma unroll
        for (int j = 0; j < 4; j++) {
          o0.h[j] = acc[j] * il0;
          o1.h[j] = acc[4 + j] * il1;
        }
        _Float16* op = hb + r * 32 + hp * 16;  // h dead -> o
        *(h8*)op = o0.v;
        *(h8*)(op + 8) = o1.v;
      }
    }
  }
  __syncthreads();

  // ---- phase 4: ao = MFMA(o, Wo) -> aob (fp16) ----
  for (int u = wv; u < MT * 2; u += 4) {
    const int mt = u >> 1, nt = u & 1;
    h8 aO = *(const h8*)(hb + (mt * 16 + lm) * 32 + lq * 8);
    h8 bo = *(const h8*)(W16 + 3072 + (nt * 16 + lm) * 32 + lq * 8);
    fx4 acc = mfma16(aO, bo, fz);
#pragma unroll
    for (int r = 0; r < 4; r++) {
      int s = mt * 16 + lq * 4 + r;
      if (SV == SP || s < SV) aob[s * 32 + nt * 16 + lm] = (_Float16)acc[r];
    }
  }
  __syncthreads();
  // ---- phase 4 epilogue: x += rms(ao); h2 = rms(x) -> hb ----
#pragma unroll
  for (int k = 0; k < SREG; k++) {
    int r = srow + 8 * k;
    if (SV % 8 == 0 || r < SV) {
      float a = (float)aob[r * 32 + e];
      float ss = red32(a * a);
      xr[k] += a * rsqrtf(ss * (1.0f / E_) + 1e-6f) * nw1;
      float hx = xr[k];
      float s2 = red32(hx * hx);
      hb[r * 32 + e] = (_Float16)(hx * rsqrtf(s2 * (1.0f / E_) + 1e-6f) * nw2);
    }
  }
  __syncthreads();

  // ---- phase 5: ffn = silu(MFMA(h2,Wg)) * MFMA(h2,Wvl) -> ffnb ----
  for (int u = wv; u < MT * 4; u += 4) {
    const int mt = u >> 2, nt = u & 3;
    h8 aH2 = *(const h8*)(hb + (mt * 16 + lm) * 32 + lq * 8);
    h8 bg = *(const h8*)(W16 + 4096 + (nt * 16 + lm) * 32 + lq * 8);
    h8 bl = *(const h8*)(W16 + 6144 + (nt * 16 + lm) * 32 + lq * 8);
    fx4 g = mfma16(aH2, bg, fz);
    fx4 vvv = mfma16(aH2, bl, fz);
#pragma unroll
    for (int r = 0; r < 4; r++) {
      int s = mt * 16 + lq * 4 + r;
      if (SV == SP || s < SV) {
        float gg = g[r];
        float sg = gg / (1.0f + __expf(-gg));
        ffnb[s * 64 + nt * 16 + lm] = (_Float16)(sg * vvv[r]);
      }
    }
  }
  __syncthreads();

  // ---- phase 6: out = MFMA(ffn, Wout^T) [K=64 via 2 chained] -> outb ----
  for (int u = wv; u < MT * 2; u += 4) {
    const int mt = u >> 1, nt = u & 1;
    h8 a0 = *(const h8*)(ffnb + (mt * 16 + lm) * 64 + lq * 8);
    h8 a1 = *(const h8*)(ffnb + (mt * 16 + lm) * 64 + 32 + lq * 8);
    h8 b0 = *(const h8*)(W16 + 8192 + (nt * 16 + lm) * 64 + lq * 8);
    h8 b1 = *(const h8*)(W16 + 8192 + (nt * 16 + lm) * 64 + 32 + lq * 8);
    fx4 acc = mfma16(a1, b1, mfma16(a0, b0, fz));
#pragma unroll
    for (int r = 0; r < 4; r++) {
      int s = mt * 16 + lq * 4 + r;
      if (SV == SP || s < SV) outb[s * 32 + nt * 16 + lm] = (_Float16)acc[r];
    }
  }
  __syncthreads();
  // ---- phase 6 epilogue: x += rms(out), store fp16 ----
#pragma unroll
  for (int k = 0; k < SREG; k++) {
    int r = srow + 8 * k;
    if (SV % 8 == 0 || r < SV) {
      float a = (float)outb[r * 32 + e];
      float ss = red32(a * a);
      xr[k] += a * rsqrtf(ss * (1.0f / E_) + 1e-6f) * nw3;
      X[base + r * stride + e] = (_Float16)xr[k];
    }
  }
}

__global__ __launch_bounds__(256, 4) void attn_spatial_kernel(
    _Float16* __restrict__ X, const _Float16* __restrict__ W16,
    const float* __restrict__ norm4, const float* __restrict__ qkn) {
  block_body<2 * SLOTS_, 144, false>(X, W16, norm4, qkn, blockIdx.x);
}

__global__ __launch_bounds__(256, 4) void attn_temporal_kernel(
    _Float16* __restrict__ X, const _Float16* __restrict__ W16,
    const float* __restrict__ norm4, const float* __restrict__ qkn) {
  block_body<T_, 128, true>(X, W16, norm4, qkn, blockIdx.x);
}

// ---------------- final norm + output extraction ----------------
__global__ __launch_bounds__(256) void final_kernel(const _Float16* __restrict__ X,
                                                    const float* __restrict__ fnw,
                                                    float* __restrict__ out) {
  int tok = blockIdx.x * 8 + (threadIdx.x >> 5);
  int e = threadIdx.x & 31;
  if (tok >= B_ * 3) return;
  int b = tok / 3, j = tok % 3;
  const _Float16* xp = X + ((size_t)(b * T_ + (T_ - 1)) * SLOTS_ + OBS_ + j) * E_;
  float v = (float)xp[e];
  float ss = red32(v * v);
  out[j * (B_ * E_) + b * E_ + e] = v * rsqrtf(ss * (1.0f / E_) + 1e-6f) * fnw[e];
}

extern "C" void kernel_launch(void* const* d_in, const int* in_sizes, int n_in,
                              void* d_out, int out_size, void* d_ws, size_t ws_size,
                              hipStream_t stream) {
  (void)in_sizes; (void)n_in; (void)out_size; (void)ws_size;
  const float* obs          = (const float*)d_in[0];
  const float* W_val        = (const float*)d_in[1];
  const float* b_val        = (const float*)d_in[2];
  const float* input_norm_w = (const float*)d_in[3];
  const float* dim_embed    = (const float*)d_in[4];
  const float* cls_tokens   = (const float*)d_in[5];
  const float* final_norm_w = (const float*)d_in[6];
  const float* s_n4   = (const float*)d_in[14];
  const float* s_qkn  = (const float*)d_in[15];
  const float* t_n4   = (const float*)d_in[23];
  const float* t_qkn  = (const float*)d_in[24];

  _Float16* X = (_Float16*)d_ws;  // fp16 residual stream, 8.78 MB
  _Float16* W16 = (_Float16*)((char*)d_ws + X16_BYTES);  // 5*10240 halves
  float* out = (float*)d_out;

  WPtrs wp;
  wp.sWq   = (const float*)d_in[7];
  wp.sWk   = (const float*)d_in[8];
  wp.sWv   = (const float*)d_in[9];
  wp.sWo   = (const float*)d_in[10];
  wp.sWg   = (const float*)d_in[11];
  wp.sWvl  = (const float*)d_in[12];
  wp.sWout = (const float*)d_in[13];
  wp.tWq   = (const float*)d_in[16];
  wp.tWk   = (const float*)d_in[17];
  wp.tWv   = (const float*)d_in[18];
  wp.tWo   = (const float*)d_in[19];
  wp.tWg   = (const float*)d_in[20];
  wp.tWvl  = (const float*)d_in[21];
  wp.tWout = (const float*)d_in[22];
  cvt_weights_kernel<<<100, 256, 0, stream>>>(wp, W16);

  const int total_tokens = B_ * T_ * SLOTS_;
  embed_kernel<<<(total_tokens + 7) / 8, 256, 0, stream>>>(
      obs, W_val, b_val, input_norm_w, dim_embed, cls_tokens, X);

  const int N4 = 4 * E_;   // 128
  const int QN = 2 * HD_;  // 16

#define SPATIAL(i)                                                     \
  attn_spatial_kernel<<<B_ * T_ / 2, 256, 0, stream>>>(                \
      X, W16 + (i)*WBLK, s_n4 + (i)*N4, s_qkn + (i)*QN)
#define TEMPORAL(i)                                                    \
  attn_temporal_kernel<<<B_ * SLOTS_, 256, 0, stream>>>(               \
      X, W16 + (3 + (i)) * WBLK, t_n4 + (i)*N4, t_qkn + (i)*QN)

  SPATIAL(0);
  TEMPORAL(0);
  SPATIAL(1);
  TEMPORAL(1);
  SPATIAL(2);

#undef SPATIAL
#undef TEMPORAL

  final_kernel<<<6, 256, 0, stream>>>(X, final_norm_w, out);
}